// Round 14
// baseline (61.542 us; speedup 1.0000x reference)
//
#include <hip/hip_runtime.h>
#include <hip/hip_bf16.h>

// AlignmentLoss: loss = -(sum(tril(G,-1)*eq) / (sum(tril(eq,-1)) * ||tril(G,-1)||_F))
// with G = A A^T, A: 4096x1024 fp32, target: 4096 int32 (classes < 1000).
//
//   S1 = 0.5*(sum_c ||s_c||^2 - sum_i ||a_i||^2)
//   S2 = 0.5*(sum_c n_c^2 - N)
//   S3 = sum_{i>j} g_ij^2  (lower-triangle 128^2 tiles, masked Frobenius)
//   loss = -S1 / (S2 * sqrt(S3))
//
// R14: the never-tried combination -- phase-split scheduling AND full-chip
// occupancy.  R11/R12 ran 8-phase at 136 blocks = 0.53 blocks/CU (half chip
// idle); R2-R10 ran full-chip at 2-phase (m233's ~600 TF ceiling).  Here:
// 528 triangle blocks (2/CU), BK=64 dbuf (64 KB LDS), per K-tile two phases
// {frag ds_reads + stage half of t+1 | barrier | setprio MFMA x16 | barrier},
// vmcnt(0) only at K-tile boundaries, row&7 XOR swizzle both sides.
// kfinal fused via last-block-done atomic (2 launches total).

typedef __attribute__((ext_vector_type(8))) short short8;
typedef __attribute__((ext_vector_type(4))) float f32x4;

#define N_ROWS 4096
#define D_DIM  1024
#define N_CLS  1000
#define NBLK   528         // 32*33/2 lower-triangle 128^2 tiles
#define NKT    16          // 1024 / BK, BK = 64

__device__ __forceinline__ unsigned short f2bf(float f) {
  unsigned u = __float_as_uint(f);
  u += 0x7fffu + ((u >> 16) & 1u);   // round-to-nearest-even
  return (unsigned short)(u >> 16);
}

__device__ __forceinline__ void gload16(const short* g, const char* l) {
  __builtin_amdgcn_global_load_lds(
      (const __attribute__((address_space(1))) unsigned*)g,
      (__attribute__((address_space(3))) unsigned*)(void*)l, 16, 0, 0);
}

// ---------------------------------------------------------------------------
// kconv: blocks 0..511 = convert A->bf16 + fp64 row-norm partials (+ block 0
// zeroes the done-counter); blocks 512.. = per-class sum-norm + count.
// ---------------------------------------------------------------------------
__global__ void __launch_bounds__(256) kconv(const float* __restrict__ A,
                                             const int* __restrict__ target,
                                             short* __restrict__ Ab,
                                             double* __restrict__ rowp,
                                             double* __restrict__ cssp,
                                             int* __restrict__ cntp,
                                             unsigned* __restrict__ done) {
  const int tid = threadIdx.x, lane = tid & 63, w = tid >> 6;

  if (blockIdx.x < 512) {
    if (blockIdx.x == 0 && tid == 0) *done = 0u;   // reset every call
    __shared__ double wr2[4];
    const int row0 = blockIdx.x * 8;
    double ls = 0.0;
#pragma unroll
    for (int rr = 0; rr < 2; ++rr) {
      const int i = row0 + w * 2 + rr;
      const float4* src = (const float4*)(A + (size_t)i * D_DIM);
      short4* dst = (short4*)(Ab + (size_t)i * D_DIM);
      float s = 0.f;
#pragma unroll
      for (int c = 0; c < 4; ++c) {
        const float4 v = src[lane + c * 64];
        s += v.x * v.x + v.y * v.y + v.z * v.z + v.w * v.w;
        short4 o;
        o.x = (short)f2bf(v.x); o.y = (short)f2bf(v.y);
        o.z = (short)f2bf(v.z); o.w = (short)f2bf(v.w);
        dst[lane + c * 64] = o;
      }
#pragma unroll
      for (int off = 32; off; off >>= 1) s += __shfl_down(s, off);
      if (lane == 0) ls += (double)s;
    }
    if (lane == 0) wr2[w] = ls;
    __syncthreads();
    if (tid == 0) rowp[blockIdx.x] = wr2[0] + wr2[1] + wr2[2] + wr2[3];
  } else {
    __shared__ int list[N_ROWS];
    __shared__ int lcnt;
    __shared__ float wred[4];
    const int c = blockIdx.x - 512;
    if (c >= N_CLS) return;
    if (tid == 0) lcnt = 0;
    __syncthreads();
    for (int j = tid; j < N_ROWS; j += 256)
      if (target[j] == c) { int p = atomicAdd(&lcnt, 1); list[p] = j; }
    __syncthreads();
    const int n = lcnt;
    float4 acc = make_float4(0.f, 0.f, 0.f, 0.f);
    for (int m = 0; m < n; ++m) {
      const float4 v = *(const float4*)(A + (size_t)list[m] * D_DIM + tid * 4);
      acc.x += v.x; acc.y += v.y; acc.z += v.z; acc.w += v.w;
    }
    float s = acc.x * acc.x + acc.y * acc.y + acc.z * acc.z + acc.w * acc.w;
#pragma unroll
    for (int off = 32; off; off >>= 1) s += __shfl_down(s, off);
    if (lane == 0) wred[w] = s;
    __syncthreads();
    if (tid == 0) {
      cssp[c] = (double)(wred[0] + wred[1] + wred[2] + wred[3]);
      cntp[c] = n;
    }
  }
}

// ---------------------------------------------------------------------------
// kgram: 528 triangle 128^2 tiles, 4 waves 2x2 (64x64/wave), BK=64, dbuf,
// phase-split K-tiles, masked Frobenius; last block computes the final loss.
// ---------------------------------------------------------------------------
__global__ void __launch_bounds__(256, 2) kgram(const short* __restrict__ Ab,
                                                double* __restrict__ frobp,
                                                const double* __restrict__ rowp,
                                                const double* __restrict__ cssp,
                                                const int* __restrict__ cntp,
                                                unsigned* __restrict__ done,
                                                float* __restrict__ out) {
  __shared__ __align__(16) short As[2][128 * 64];   // 2 x 16 KB
  __shared__ __align__(16) short Bs[2][128 * 64];   // 2 x 16 KB
  const int tid = threadIdx.x, lane = tid & 63, w = tid >> 6;

  // XCD swizzle: 528 = 8 * 66 (bijective)
  const int b = (blockIdx.x & 7) * 66 + (blockIdx.x >> 3);
  int bi = (int)((sqrtf(8.f * (float)b + 1.f) - 1.f) * 0.5f);
  while ((bi + 1) * (bi + 2) / 2 <= b) ++bi;
  while (bi * (bi + 1) / 2 > b) --bi;
  const int bj = b - bi * (bi + 1) / 2;
  const bool diag = (bi == bj);

  const short* Pa = Ab + (size_t)(bi * 128) * D_DIM;
  const short* Pb = Ab + (size_t)(bj * 128) * D_DIM;

  f32x4 acc[4][4];
#pragma unroll
  for (int m = 0; m < 4; ++m)
#pragma unroll
    for (int n = 0; n < 4; ++n) acc[m][n] = (f32x4){0.f, 0.f, 0.f, 0.f};

  const int wm = w >> 1, wn = w & 1;       // wave tile 64x64
  const int row16 = lane & 15, ck = lane >> 4;

  // staging: issue i covers rows i*32..i*32+31; thread -> row tid>>3,
  // 16B-chunk tid&7 pre-swizzled by row&7 (rule #21: LDS linear).
  const int srow = tid >> 3;               // 0..31
  const int scol = (tid & 7) ^ (srow & 7);

#define STAGE4(P, BASE, kt)                                                 \
  do {                                                                      \
    _Pragma("unroll")                                                       \
    for (int i = 0; i < 4; ++i)                                             \
      gload16((P) + (size_t)(i * 32 + srow) * D_DIM + (kt) * 64 + scol * 8, \
              (BASE) + i * 4096 + w * 1024);                                \
  } while (0)

  // frag read: row R, k-slice col16 (= ks*4+ck); byte = R*128 + (col16^(R&7))*16
#define FRAG(BASE, R, ks)                                                   \
  (*(const short8*)((const char*)(BASE) + (R) * 128 +                       \
                    ((((ks) * 4 + ck) ^ ((R) & 7)) << 4)))

  STAGE4(Pa, (char*)As[0], 0);
  STAGE4(Pb, (char*)Bs[0], 0);
  asm volatile("s_waitcnt vmcnt(0)" ::: "memory");
  __builtin_amdgcn_sched_barrier(0);
  __builtin_amdgcn_s_barrier();

  int cur = 0;
#pragma unroll 1
  for (int t = 0; t < NKT; ++t) {
    short8 a[2][4], bb[2][4];
    // ---- phase 1: read A frags + B cols 0..1 ; stage A of t+1
#pragma unroll
    for (int ks = 0; ks < 2; ++ks)
#pragma unroll
      for (int m = 0; m < 4; ++m)
        a[ks][m] = FRAG(As[cur], wm * 64 + m * 16 + row16, ks);
#pragma unroll
    for (int ks = 0; ks < 2; ++ks)
#pragma unroll
      for (int n = 0; n < 2; ++n)
        bb[ks][n] = FRAG(Bs[cur], wn * 64 + n * 16 + row16, ks);
    if (t < NKT - 1) STAGE4(Pa, (char*)As[cur ^ 1], t + 1);
    __builtin_amdgcn_s_barrier();
    __builtin_amdgcn_s_setprio(1);
#pragma unroll
    for (int ks = 0; ks < 2; ++ks)
#pragma unroll
      for (int m = 0; m < 4; ++m)
#pragma unroll
        for (int n = 0; n < 2; ++n)
          acc[m][n] = __builtin_amdgcn_mfma_f32_16x16x32_bf16(
              a[ks][m], bb[ks][n], acc[m][n], 0, 0, 0);
    __builtin_amdgcn_s_setprio(0);
    __builtin_amdgcn_s_barrier();
    // ---- phase 2: read B cols 2..3 ; stage B of t+1
#pragma unroll
    for (int ks = 0; ks < 2; ++ks)
#pragma unroll
      for (int n = 0; n < 2; ++n)
        bb[ks][n] = FRAG(Bs[cur], wn * 64 + (n + 2) * 16 + row16, ks);
    if (t < NKT - 1) STAGE4(Pb, (char*)Bs[cur ^ 1], t + 1);
    __builtin_amdgcn_s_barrier();
    __builtin_amdgcn_s_setprio(1);
#pragma unroll
    for (int ks = 0; ks < 2; ++ks)
#pragma unroll
      for (int m = 0; m < 4; ++m)
#pragma unroll
        for (int n = 0; n < 2; ++n)
          acc[m][n + 2] = __builtin_amdgcn_mfma_f32_16x16x32_bf16(
              a[ks][m], bb[ks][n], acc[m][n + 2], 0, 0, 0);
    __builtin_amdgcn_s_setprio(0);
    __builtin_amdgcn_s_barrier();
    // ---- K-tile boundary: t+1's 8 staged loads must be resident
    asm volatile("s_waitcnt vmcnt(0)" ::: "memory");
    __builtin_amdgcn_sched_barrier(0);
    __builtin_amdgcn_s_barrier();
    cur ^= 1;
  }
#undef STAGE4
#undef FRAG

  // masked Frobenius
  float fs = 0.f;
  if (!diag) {
#pragma unroll
    for (int m = 0; m < 4; ++m)
#pragma unroll
      for (int n = 0; n < 4; ++n)
#pragma unroll
        for (int q = 0; q < 4; ++q) fs += acc[m][n][q] * acc[m][n][q];
  } else {
    const int rbase = (lane >> 4) * 4, cbase = lane & 15;
#pragma unroll
    for (int m = 0; m < 4; ++m)
#pragma unroll
      for (int n = 0; n < 4; ++n)
#pragma unroll
        for (int q = 0; q < 4; ++q) {
          const int rl = wm * 64 + m * 16 + rbase + q;
          const int cl = wn * 64 + n * 16 + cbase;
          if (rl > cl) fs += acc[m][n][q] * acc[m][n][q];
        }
  }
#pragma unroll
  for (int off = 32; off; off >>= 1) fs += __shfl_down(fs, off);

  __syncthreads();                         // LDS reuse
  double* red = (double*)As;               // 256 doubles scratch
  __shared__ bool last;
  if (lane == 0) red[w] = (double)fs;
  __syncthreads();
  if (tid == 0) {
    frobp[b] = red[0] + red[1] + red[2] + red[3];
    __threadfence();
    last = (atomicAdd(done, 1u) == NBLK - 1);
  }
  __syncthreads();
  if (!last) return;

  // ---- last block: final reduction + scalar math ----
  double lsum = rowp[tid] + rowp[tid + 256];
  double lcss = 0.0, lcnn = 0.0, lfr = 0.0;
  for (int c = tid; c < N_CLS; c += 256) {
    lcss += cssp[c];
    const double nc = (double)cntp[c];
    lcnn += nc * nc;
  }
  for (int c = tid; c < NBLK; c += 256)
    lfr += atomicAdd(&frobp[c], 0.0);      // device-coherent read
  double vals[4] = {lsum, lcss, lcnn, lfr};
  double res[4];
  for (int v = 0; v < 4; ++v) {
    red[tid] = vals[v];
    __syncthreads();
    for (int s = 128; s; s >>= 1) {
      if (tid < s) red[tid] += red[tid + s];
      __syncthreads();
    }
    res[v] = red[0];
    __syncthreads();
  }
  if (tid == 0) {
    const double S1 = 0.5 * (res[1] - res[0]);
    const double S2 = 0.5 * (res[2] - (double)N_ROWS);
    out[0] = (float)(-(S1 / (S2 * sqrt(res[3]))));
  }
}

extern "C" void kernel_launch(void* const* d_in, const int* in_sizes, int n_in,
                              void* d_out, int out_size, void* d_ws, size_t ws_size,
                              hipStream_t stream) {
  const float* A = (const float*)d_in[0];
  const int* target = (const int*)d_in[1];
  float* out = (float*)d_out;

  char* ws = (char*)d_ws;
  short*    Ab    = (short*)ws;                    // 8,388,608 B
  double*   rowp  = (double*)(ws + 8388608);       // 512 doubles
  double*   cssp  = (double*)(ws + 8392704);       // 1000 doubles
  int*      cntp  = (int*)   (ws + 8400704);       // 1000 ints
  double*   frobp = (double*)(ws + 8404736);       // 528 doubles
  unsigned* done  = (unsigned*)(ws + 8408960);     // 1 uint

  kconv<<<512 + N_CLS, 256, 0, stream>>>(A, target, Ab, rowp, cssp, cntp, done);
  kgram<<<NBLK, 256, 0, stream>>>(Ab, frobp, rowp, cssp, cntp, done, out);
}

// Round 15
// 54.585 us; speedup vs baseline: 1.1274x; 1.1274x over previous
//
#include <hip/hip_runtime.h>
#include <hip/hip_bf16.h>

// AlignmentLoss: loss = -(sum(tril(G,-1)*eq) / (sum(tril(eq,-1)) * ||tril(G,-1)||_F))
// with G = A A^T, A: 4096x1024 fp32, target: 4096 int32 (classes < 1000).
//
//   S1 = 0.5*(sum_c ||s_c||^2 - sum_i ||a_i||^2)
//   S2 = 0.5*(sum_c n_c^2 - N)
//   S3 = sum_{i>j} g_ij^2  (lower-triangle 128^2 tiles, masked Frobenius)
//   loss = -S1 / (S2 * sqrt(S3))
//
// R15: revert to the R7 best (46.0 us) -- kprep + kfrob(8 waves 2x4 of 64x32,
// LDS dbuf, counted vmcnt(2), both-sides bank swizzle, XCD swizzle) -- plus
// the one R14 element that worked: last-block-done atomic finalize inside
// kfrob (R14-proven coherent).  2 launches instead of 4; K-loop untouched.

typedef __attribute__((ext_vector_type(8))) short short8;
typedef __attribute__((ext_vector_type(4))) float f32x4;

#define N_ROWS 4096
#define D_DIM  1024
#define N_CLS  1000
#define NBLK   528         // 32*33/2 lower-triangle 128^2 tiles
#define NK     32          // 1024 / BK,  BK = 32

__device__ __forceinline__ unsigned short f2bf(float f) {
  unsigned u = __float_as_uint(f);
  u += 0x7fffu + ((u >> 16) & 1u);   // round-to-nearest-even
  return (unsigned short)(u >> 16);
}

__device__ __forceinline__ void gload16(const short* g, const char* l) {
  __builtin_amdgcn_global_load_lds(
      (const __attribute__((address_space(1))) unsigned*)g,
      (__attribute__((address_space(3))) unsigned*)(void*)l, 16, 0, 0);
}

// ---------------------------------------------------------------------------
// kprep: blocks 0..511 = convert A->bf16 + fp64 row-norm partials (block 0
// also zeroes the done counter); blocks 512.. = per-class sum-norm + count.
// ---------------------------------------------------------------------------
__global__ void __launch_bounds__(256) kprep(const float* __restrict__ A,
                                             const int* __restrict__ target,
                                             short* __restrict__ Ab,
                                             double* __restrict__ rowp,
                                             double* __restrict__ cssp,
                                             int* __restrict__ cntp,
                                             unsigned* __restrict__ done) {
  const int tid = threadIdx.x, lane = tid & 63, w = tid >> 6;

  if (blockIdx.x < 512) {
    if (blockIdx.x == 0 && tid == 0) *done = 0u;   // reset every call
    __shared__ double wr2[4];
    const int row0 = blockIdx.x * 8;
    double ls = 0.0;
#pragma unroll
    for (int rr = 0; rr < 2; ++rr) {
      const int i = row0 + w * 2 + rr;
      const float4* src = (const float4*)(A + (size_t)i * D_DIM);
      short4* dst = (short4*)(Ab + (size_t)i * D_DIM);
      float s = 0.f;
#pragma unroll
      for (int c = 0; c < 4; ++c) {
        const float4 v = src[lane + c * 64];
        s += v.x * v.x + v.y * v.y + v.z * v.z + v.w * v.w;
        short4 o;
        o.x = (short)f2bf(v.x); o.y = (short)f2bf(v.y);
        o.z = (short)f2bf(v.z); o.w = (short)f2bf(v.w);
        dst[lane + c * 64] = o;
      }
#pragma unroll
      for (int off = 32; off; off >>= 1) s += __shfl_down(s, off);
      if (lane == 0) ls += (double)s;
    }
    if (lane == 0) wr2[w] = ls;
    __syncthreads();
    if (tid == 0) rowp[blockIdx.x] = wr2[0] + wr2[1] + wr2[2] + wr2[3];
  } else {
    __shared__ int list[N_ROWS];
    __shared__ int lcnt;
    __shared__ float wred[4];
    const int c = blockIdx.x - 512;
    if (c >= N_CLS) return;
    if (tid == 0) lcnt = 0;
    __syncthreads();
    for (int j = tid; j < N_ROWS; j += 256)
      if (target[j] == c) { int p = atomicAdd(&lcnt, 1); list[p] = j; }
    __syncthreads();
    const int n = lcnt;
    float4 acc = make_float4(0.f, 0.f, 0.f, 0.f);
    for (int m = 0; m < n; ++m) {
      const float4 v = *(const float4*)(A + (size_t)list[m] * D_DIM + tid * 4);
      acc.x += v.x; acc.y += v.y; acc.z += v.z; acc.w += v.w;
    }
    float s = acc.x * acc.x + acc.y * acc.y + acc.z * acc.z + acc.w * acc.w;
#pragma unroll
    for (int off = 32; off; off >>= 1) s += __shfl_down(s, off);
    if (lane == 0) wred[w] = s;
    __syncthreads();
    if (tid == 0) {
      cssp[c] = (double)(wred[0] + wred[1] + wred[2] + wred[3]);
      cntp[c] = n;
    }
  }
}

// ---------------------------------------------------------------------------
// kfrob: R7's exact kernel -- lower-triangle 128x128 tiles of G = Ab*Ab^T,
// bf16 MFMA, 8 waves (2x4, 64x32 per wave), LDS dbuf + counted-vmcnt(2),
// bank-swizzled both sides, XCD-swizzled map, fused masked Frobenius.
// Last finished block performs the final fp64 reduction + scalar math.
// ---------------------------------------------------------------------------
__global__ void __launch_bounds__(512, 4) kfrob(const short* __restrict__ Ab,
                                                double* __restrict__ frobp,
                                                const double* __restrict__ rowp,
                                                const double* __restrict__ cssp,
                                                const int* __restrict__ cntp,
                                                unsigned* __restrict__ done,
                                                float* __restrict__ out) {
  __shared__ __align__(16) short As[2][128 * 32];   // 2 x 8 KB
  __shared__ __align__(16) short Bs[2][128 * 32];   // 2 x 8 KB
  __shared__ bool last;
  const int tid = threadIdx.x, lane = tid & 63, w = tid >> 6;

  // XCD-aware swizzle: 528 = 8 * 66; XCD x gets contiguous triangle chunk.
  const int b = (blockIdx.x & 7) * 66 + (blockIdx.x >> 3);

  // decode lower-triangle pair: b = bi*(bi+1)/2 + bj, bj <= bi
  int bi = (int)((sqrtf(8.f * (float)b + 1.f) - 1.f) * 0.5f);
  while ((bi + 1) * (bi + 2) / 2 <= b) ++bi;
  while (bi * (bi + 1) / 2 > b) --bi;
  const int bj = b - bi * (bi + 1) / 2;
  const bool diag = (bi == bj);

  const short* Pa = Ab + (size_t)(bi * 128) * D_DIM;
  const short* Pb = Ab + (size_t)(bj * 128) * D_DIM;

  f32x4 acc[4][2];
#pragma unroll
  for (int m = 0; m < 4; ++m)
#pragma unroll
    for (int n = 0; n < 2; ++n) acc[m][n] = (f32x4){0.f, 0.f, 0.f, 0.f};

  const int wr = w >> 2, wc = w & 3;             // wave tile: rows 64*wr, cols 32*wc
  const int row16 = lane & 15, ck = lane >> 4;   // ck = 16-B chunk index 0..3

  // staging: 512 thr x 16B = one full [128][32]-short buffer per issue.
  // Source chunk pre-swizzled (chunk ^= (row>>1)&3); LDS linear (rule #21).
  const int sr = tid >> 2, sc = tid & 3;
  const int scS = sc ^ ((sr >> 1) & 3);
  const size_t gofs = (size_t)sr * D_DIM + scS * 8;
  const int lofs = w * 1024;                     // = tid*16 - lane*16 (linear)

#define STAGE(buf, k0)                                                      \
  do {                                                                      \
    gload16(Pa + gofs + (k0), (const char*)As[buf] + lofs);                 \
    gload16(Pb + gofs + (k0), (const char*)Bs[buf] + lofs);                 \
  } while (0)

  // swizzled ds_read offset (in shorts) for row R, chunk ck
#define SWZ(R) (((R) * 32) + ((ck ^ (((R) >> 1) & 3)) * 8))

#define COMPUTE(buf)                                                        \
  do {                                                                      \
    short8 af[4], bf[2];                                                    \
    _Pragma("unroll")                                                       \
    for (int m = 0; m < 4; ++m)                                             \
      af[m] = *(const short8*)&As[buf][SWZ(wr * 64 + m * 16 + row16)];      \
    _Pragma("unroll")                                                       \
    for (int n = 0; n < 2; ++n)                                             \
      bf[n] = *(const short8*)&Bs[buf][SWZ(wc * 32 + n * 16 + row16)];      \
    _Pragma("unroll")                                                       \
    for (int m = 0; m < 4; ++m)                                             \
      _Pragma("unroll")                                                     \
      for (int n = 0; n < 2; ++n)                                           \
        acc[m][n] = __builtin_amdgcn_mfma_f32_16x16x32_bf16(af[m], bf[n],   \
                                                            acc[m][n], 0, 0, 0);\
  } while (0)

  STAGE(0, 0);                       // prologue: tile 0 in flight
  int cur = 0;
#pragma unroll 1
  for (int t = 0; t < NK - 1; ++t) {
    STAGE(cur ^ 1, (t + 1) * 32);    // issue next tile (2 loads/thread)
    asm volatile("s_waitcnt vmcnt(2)" ::: "memory");   // wait tile t only
    __builtin_amdgcn_sched_barrier(0);
    __builtin_amdgcn_s_barrier();    // all waves: tile t resident
    __builtin_amdgcn_sched_barrier(0);
    COMPUTE(cur);
    asm volatile("s_waitcnt lgkmcnt(0)" ::: "memory"); // all ds_reads retired
    __builtin_amdgcn_sched_barrier(0);
    __builtin_amdgcn_s_barrier();    // safe to overwrite buf cur next iter
    __builtin_amdgcn_sched_barrier(0);
    cur ^= 1;
  }
  asm volatile("s_waitcnt vmcnt(0)" ::: "memory");     // last tile resident
  __builtin_amdgcn_sched_barrier(0);
  __builtin_amdgcn_s_barrier();
  __builtin_amdgcn_sched_barrier(0);
  COMPUTE(cur);
#undef STAGE
#undef COMPUTE
#undef SWZ

  float fs = 0.f;
  if (!diag) {
#pragma unroll
    for (int m = 0; m < 4; ++m)
#pragma unroll
      for (int n = 0; n < 2; ++n)
#pragma unroll
        for (int q = 0; q < 4; ++q) fs += acc[m][n][q] * acc[m][n][q];
  } else {
    const int rbase = (lane >> 4) * 4, cbase = lane & 15;
#pragma unroll
    for (int m = 0; m < 4; ++m)
#pragma unroll
      for (int n = 0; n < 2; ++n)
#pragma unroll
        for (int q = 0; q < 4; ++q) {
          const int rl = wr * 64 + m * 16 + rbase + q;
          const int cl = wc * 32 + n * 16 + cbase;
          if (rl > cl) fs += acc[m][n][q] * acc[m][n][q];
        }
  }
#pragma unroll
  for (int off = 32; off; off >>= 1) fs += __shfl_down(fs, off);

  __syncthreads();                   // K-loop done; reuse As as scratch
  double* red = (double*)As;         // 512 doubles = 4 KB
  if (lane == 0) red[w] = (double)fs;
  __syncthreads();
  if (tid == 0) {
    double t = 0.0;
#pragma unroll
    for (int i = 0; i < 8; ++i) t += red[i];
    frobp[b] = t;
    __threadfence();
    last = (atomicAdd(done, 1u) == NBLK - 1);
  }
  __syncthreads();
  if (!last) return;

  // ---- last block: final fp64 reduction + scalar math ----
  double lsum = rowp[tid];           // 512 entries, 512 threads
  double lcss = 0.0, lcnn = 0.0, lfr = 0.0;
  for (int c = tid; c < N_CLS; c += 512) {
    lcss += cssp[c];
    const double nc = (double)cntp[c];
    lcnn += nc * nc;
  }
  for (int c = tid; c < NBLK; c += 512)
    lfr += atomicAdd(&frobp[c], 0.0);        // device-coherent read
  double vals[4] = {lsum, lcss, lcnn, lfr};
  double res[4];
  for (int v = 0; v < 4; ++v) {
    red[tid] = vals[v];
    __syncthreads();
    for (int s = 256; s; s >>= 1) {
      if (tid < s) red[tid] += red[tid + s];
      __syncthreads();
    }
    res[v] = red[0];
    __syncthreads();
  }
  if (tid == 0) {
    const double S1 = 0.5 * (res[1] - res[0]);
    const double S2 = 0.5 * (res[2] - (double)N_ROWS);
    out[0] = (float)(-(S1 / (S2 * sqrt(res[3]))));
  }
}

extern "C" void kernel_launch(void* const* d_in, const int* in_sizes, int n_in,
                              void* d_out, int out_size, void* d_ws, size_t ws_size,
                              hipStream_t stream) {
  const float* A = (const float*)d_in[0];
  const int* target = (const int*)d_in[1];
  float* out = (float*)d_out;

  char* ws = (char*)d_ws;
  short*    Ab    = (short*)ws;                    // 8,388,608 B
  double*   rowp  = (double*)(ws + 8388608);       // 512 doubles
  double*   cssp  = (double*)(ws + 8392704);       // 1000 doubles
  int*      cntp  = (int*)   (ws + 8400704);       // 1000 ints
  double*   frobp = (double*)(ws + 8404736);       // 528 doubles
  unsigned* done  = (unsigned*)(ws + 8408960);     // 1 uint

  kprep<<<512 + N_CLS, 256, 0, stream>>>(A, target, Ab, rowp, cssp, cntp, done);
  kfrob<<<NBLK, 512, 0, stream>>>(Ab, frobp, rowp, cssp, cntp, done, out);
}

// Round 16
// 49.262 us; speedup vs baseline: 1.2493x; 1.1081x over previous
//
#include <hip/hip_runtime.h>
#include <hip/hip_bf16.h>

// AlignmentLoss: loss = -(sum(tril(G,-1)*eq) / (sum(tril(eq,-1)) * ||tril(G,-1)||_F))
// with G = A A^T, A: 4096x1024 fp32, target: 4096 int32 (classes < 1000).
//
//   S1 = 0.5*(sum_c ||s_c||^2 - sum_i ||a_i||^2)
//   S2 = 0.5*(sum_c n_c^2 - N)
//   S3 = sum_{i>j} g_ij^2  (lower-triangle 256^2 tiles, masked Frobenius)
//   loss = -S1 / (S2 * sqrt(S3))
//
// R16: recombination of the two best-measured configurations, no new ideas.
//  - kprep: R6/R7's verified conv+class mega-launch (256 thr) -- class work
//    overlaps the BW-bound convert with hot-A L2 locality.
//  - kgram: R12's 8-phase 256^2 gram VERBATIM, gram-only grid (136 blocks).
//  - kfinal: separate launch (R15 proved fusion regresses).

typedef __attribute__((ext_vector_type(8))) short short8;
typedef __attribute__((ext_vector_type(4))) float f32x4;

#define N_ROWS 4096
#define D_DIM  1024
#define N_CLS  1000
#define NTIL   136         // 16*17/2 lower-triangle 256^2 tiles

__device__ __forceinline__ unsigned short f2bf(float f) {
  unsigned u = __float_as_uint(f);
  u += 0x7fffu + ((u >> 16) & 1u);   // round-to-nearest-even
  return (unsigned short)(u >> 16);
}

__device__ __forceinline__ void gload16(const short* g, const char* l) {
  __builtin_amdgcn_global_load_lds(
      (const __attribute__((address_space(1))) unsigned*)g,
      (__attribute__((address_space(3))) unsigned*)(void*)l, 16, 0, 0);
}

// ---------------------------------------------------------------------------
// kprep: blocks 0..511 = convert A->bf16 + fp64 row-norm partials
//        blocks 512..  = per-class sum-vector norm + count
// ---------------------------------------------------------------------------
__global__ void __launch_bounds__(256) kprep(const float* __restrict__ A,
                                             const int* __restrict__ target,
                                             short* __restrict__ Ab,
                                             double* __restrict__ rowp,
                                             double* __restrict__ cssp,
                                             int* __restrict__ cntp) {
  const int tid = threadIdx.x, lane = tid & 63, w = tid >> 6;

  if (blockIdx.x < 512) {
    __shared__ double wr2[4];
    const int row0 = blockIdx.x * 8;
    double ls = 0.0;
#pragma unroll
    for (int rr = 0; rr < 2; ++rr) {
      const int i = row0 + w * 2 + rr;
      const float4* src = (const float4*)(A + (size_t)i * D_DIM);
      short4* dst = (short4*)(Ab + (size_t)i * D_DIM);
      float s = 0.f;
#pragma unroll
      for (int c = 0; c < 4; ++c) {
        const float4 v = src[lane + c * 64];
        s += v.x * v.x + v.y * v.y + v.z * v.z + v.w * v.w;
        short4 o;
        o.x = (short)f2bf(v.x); o.y = (short)f2bf(v.y);
        o.z = (short)f2bf(v.z); o.w = (short)f2bf(v.w);
        dst[lane + c * 64] = o;
      }
#pragma unroll
      for (int off = 32; off; off >>= 1) s += __shfl_down(s, off);
      if (lane == 0) ls += (double)s;
    }
    if (lane == 0) wr2[w] = ls;
    __syncthreads();
    if (tid == 0) rowp[blockIdx.x] = wr2[0] + wr2[1] + wr2[2] + wr2[3];
  } else {
    __shared__ int list[N_ROWS];
    __shared__ int lcnt;
    __shared__ float wred[4];
    const int c = blockIdx.x - 512;
    if (c >= N_CLS) return;
    if (tid == 0) lcnt = 0;
    __syncthreads();
    for (int j = tid; j < N_ROWS; j += 256)
      if (target[j] == c) { int p = atomicAdd(&lcnt, 1); list[p] = j; }
    __syncthreads();
    const int n = lcnt;
    float4 acc = make_float4(0.f, 0.f, 0.f, 0.f);
    for (int m = 0; m < n; ++m) {
      const float4 v = *(const float4*)(A + (size_t)list[m] * D_DIM + tid * 4);
      acc.x += v.x; acc.y += v.y; acc.z += v.z; acc.w += v.w;
    }
    float s = acc.x * acc.x + acc.y * acc.y + acc.z * acc.z + acc.w * acc.w;
#pragma unroll
    for (int off = 32; off; off >>= 1) s += __shfl_down(s, off);
    if (lane == 0) wred[w] = s;
    __syncthreads();
    if (tid == 0) {
      cssp[c] = (double)(wred[0] + wred[1] + wred[2] + wred[3]);
      cntp[c] = n;
    }
  }
}

// ---------------------------------------------------------------------------
// kgram: R12's 8-phase 256^2 gram, gram-only grid.  512 thr (8 waves 2x4,
// 128x64 per wave), BK=64, 128 KB LDS (2 bufs x {A,B}), per K-tile 4
// quadrant-phases of 16 MFMA between raw s_barriers, stages spread 2/phase
// into the other buffer >=2 phases ahead, vmcnt(0) only at K-tile
// boundaries, setprio around MFMA, both-sides XOR swizzle, XCD swizzle.
// ---------------------------------------------------------------------------
__global__ void __launch_bounds__(512, 2) kgram(const short* __restrict__ Ab,
                                                double* __restrict__ frobp) {
  __shared__ __align__(16) char smem[131072];   // 128 KB pool
  const int tid = threadIdx.x, lane = tid & 63, w = tid >> 6;

  // bijective XCD swizzle: 136 = 8 * 17
  const int b = (blockIdx.x & 7) * 17 + (blockIdx.x >> 3);
  int bi = (int)((sqrtf(8.f * (float)b + 1.f) - 1.f) * 0.5f);
  while ((bi + 1) * (bi + 2) / 2 <= b) ++bi;
  while (bi * (bi + 1) / 2 > b) --bi;
  const int bj = b - bi * (bi + 1) / 2;
  const bool diag = (bi == bj);

  const short* Pa = Ab + (size_t)(bi * 256) * D_DIM;
  const short* Pb = Ab + (size_t)(bj * 256) * D_DIM;

  // LDS: per buf per matrix 32 KB = [2 ksub][256 rows][64 B]
  short* As0 = (short*)smem;
  short* As1 = (short*)(smem + 32768);
  short* Bs0 = (short*)(smem + 65536);
  short* Bs1 = (short*)(smem + 98304);

  f32x4 acc[8][4];
#pragma unroll
  for (int m = 0; m < 8; ++m)
#pragma unroll
    for (int n = 0; n < 4; ++n) acc[m][n] = (f32x4){0.f, 0.f, 0.f, 0.f};

  const int wm = w >> 2, wn = w & 3;       // wave: rows wm*128, cols wn*64
  const int row16 = lane & 15, ck = lane >> 4;

  // staging: unit = (matrix, half h, K-tile kt): 2 gload16/thread (16 KB)
  const int sr = tid >> 2;                 // 0..127
  const int scS = (tid & 3) ^ ((sr >> 1) & 3);

#define STAGEU(P, BUF, h, kt)                                               \
  do {                                                                      \
    const short* _g = (P) + ((size_t)((h) * 128 + sr)) * D_DIM + (kt) * 64 + scS * 8; \
    gload16(_g,      (const char*)(BUF) + (h) * 8192 + w * 1024);           \
    gload16(_g + 32, (const char*)(BUF) + 16384 + (h) * 8192 + w * 1024);   \
  } while (0)

#define RD_A(BUF, MH)                                                       \
  _Pragma("unroll") for (int ks = 0; ks < 2; ++ks)                          \
  _Pragma("unroll") for (int m = 0; m < 4; ++m) {                           \
    const int R = wm * 128 + ((MH) * 4 + m) * 16 + row16;                   \
    a[ks][m] = *(const short8*)((const char*)(BUF) + ks * 16384 + R * 64    \
                                + ((ck ^ ((R >> 1) & 3)) << 4));            \
  }
#define RD_B(DST, BUF, NH)                                                  \
  _Pragma("unroll") for (int ks = 0; ks < 2; ++ks)                          \
  _Pragma("unroll") for (int n = 0; n < 2; ++n) {                           \
    const int R = wn * 64 + ((NH) * 2 + n) * 16 + row16;                    \
    DST[ks][n] = *(const short8*)((const char*)(BUF) + ks * 16384 + R * 64  \
                                  + ((ck ^ ((R >> 1) & 3)) << 4));          \
  }
#define PH_MFMA(MO, NO, BB)                                                 \
  __builtin_amdgcn_s_setprio(1);                                            \
  _Pragma("unroll") for (int ks = 0; ks < 2; ++ks)                          \
  _Pragma("unroll") for (int m = 0; m < 4; ++m)                             \
  _Pragma("unroll") for (int n = 0; n < 2; ++n)                             \
    acc[(MO) + m][(NO) + n] = __builtin_amdgcn_mfma_f32_16x16x32_bf16(      \
        a[ks][m], BB[ks][n], acc[(MO) + m][(NO) + n], 0, 0, 0);             \
  __builtin_amdgcn_s_setprio(0);
#define BAR __builtin_amdgcn_s_barrier()
#define VM0 asm volatile("s_waitcnt vmcnt(0)" ::: "memory")

  // prologue: K-tile 0 -> buf0
  STAGEU(Pa, As0, 0, 0); STAGEU(Pa, As0, 1, 0);
  STAGEU(Pb, Bs0, 0, 0); STAGEU(Pb, Bs0, 1, 0);
  VM0;
  BAR;

#pragma unroll 1
  for (int it = 0; it < 8; ++it) {
    const int t1 = 2 * it + 1, t2 = 2 * it + 2;
    short8 a[2][4], bq0[2][2], b[2][2];
    // ---- ph1: t0 q0 (buf0) ; stage A of t1 -> buf1
    RD_A(As0, 0); RD_B(bq0, Bs0, 0);
    STAGEU(Pa, As1, 0, t1); STAGEU(Pa, As1, 1, t1);
    BAR;
    PH_MFMA(0, 0, bq0);
    BAR;
    // ---- ph2: q1 ; stage B of t1 -> buf1
    RD_B(b, Bs0, 1);
    STAGEU(Pb, Bs1, 0, t1); STAGEU(Pb, Bs1, 1, t1);
    BAR;
    PH_MFMA(0, 2, b);
    BAR;
    // ---- ph3: q2
    RD_A(As0, 1);
    BAR;
    PH_MFMA(4, 2, b);
    BAR;
    // ---- ph4: q3 (no reads/stages)
    PH_MFMA(4, 0, bq0);
    BAR;
    VM0;                 // t1's units (staged ph1-2) resident everywhere
    BAR;
    // ---- ph5: t1 q0 (buf1) ; stage A of t2 -> buf0 (freed after ph4)
    RD_A(As1, 0); RD_B(bq0, Bs1, 0);
    if (it < 7) { STAGEU(Pa, As0, 0, t2); STAGEU(Pa, As0, 1, t2); }
    BAR;
    PH_MFMA(0, 0, bq0);
    BAR;
    // ---- ph6: q1 ; stage B of t2 -> buf0
    RD_B(b, Bs1, 1);
    if (it < 7) { STAGEU(Pb, Bs0, 0, t2); STAGEU(Pb, Bs0, 1, t2); }
    BAR;
    PH_MFMA(0, 2, b);
    BAR;
    // ---- ph7: q2
    RD_A(As1, 1);
    BAR;
    PH_MFMA(4, 2, b);
    BAR;
    // ---- ph8: q3
    PH_MFMA(4, 0, bq0);
    BAR;
    VM0;                 // t2's units (staged ph5-6) resident
    BAR;
  }
#undef STAGEU
#undef RD_A
#undef RD_B
#undef PH_MFMA
#undef BAR
#undef VM0

  // epilogue: masked Frobenius
  float fs = 0.f;
  if (!diag) {
#pragma unroll
    for (int m = 0; m < 8; ++m)
#pragma unroll
      for (int n = 0; n < 4; ++n)
#pragma unroll
        for (int q = 0; q < 4; ++q) fs += acc[m][n][q] * acc[m][n][q];
  } else {
    const int rbase = (lane >> 4) * 4, cbase = lane & 15;
#pragma unroll
    for (int m = 0; m < 8; ++m)
#pragma unroll
      for (int n = 0; n < 4; ++n)
#pragma unroll
        for (int q = 0; q < 4; ++q) {
          const int rl = wm * 128 + m * 16 + rbase + q;
          const int cl = wn * 64 + n * 16 + cbase;
          if (rl > cl) fs += acc[m][n][q] * acc[m][n][q];
        }
  }
#pragma unroll
  for (int off = 32; off; off >>= 1) fs += __shfl_down(fs, off);
  double* wredd = (double*)smem;       // LDS free after the loop
  __syncthreads();
  if (lane == 0) wredd[w] = (double)fs;
  __syncthreads();
  if (tid == 0) {
    double t = 0.0;
#pragma unroll
    for (int i = 0; i < 8; ++i) t += wredd[i];
    frobp[b] = t;
  }
}

// ---------------------------------------------------------------------------
// kfinal: fp64 reduce + scalar math.
// ---------------------------------------------------------------------------
__global__ void __launch_bounds__(256) kfinal(const double* __restrict__ rowp,
                                              const double* __restrict__ cssp,
                                              const int* __restrict__ cntp,
                                              const double* __restrict__ frobp,
                                              float* __restrict__ out) {
  __shared__ double red[256];
  const int tid = threadIdx.x;
  double lsum = rowp[tid] + rowp[tid + 256];
  double lcss = 0.0, lcnn = 0.0, lfr = 0.0;
  for (int c = tid; c < N_CLS; c += 256) {
    lcss += cssp[c];
    const double nc = (double)cntp[c];
    lcnn += nc * nc;
  }
  if (tid < NTIL) lfr = frobp[tid];

  double vals[4] = {lsum, lcss, lcnn, lfr};
  double res[4];
  for (int v = 0; v < 4; ++v) {
    red[tid] = vals[v];
    __syncthreads();
    for (int s = 128; s; s >>= 1) {
      if (tid < s) red[tid] += red[tid + s];
      __syncthreads();
    }
    res[v] = red[0];
    __syncthreads();
  }
  if (tid == 0) {
    const double sumr = res[0], css = res[1], cnn = res[2], frob = res[3];
    const double S1 = 0.5 * (css - sumr);
    const double S2 = 0.5 * (cnn - (double)N_ROWS);
    const double S3 = frob;
    out[0] = (float)(-(S1 / (S2 * sqrt(S3))));
  }
}

extern "C" void kernel_launch(void* const* d_in, const int* in_sizes, int n_in,
                              void* d_out, int out_size, void* d_ws, size_t ws_size,
                              hipStream_t stream) {
  const float* A = (const float*)d_in[0];
  const int* target = (const int*)d_in[1];
  float* out = (float*)d_out;

  char* ws = (char*)d_ws;
  short*  Ab    = (short*)ws;                                   // 8,388,608 B
  double* rowp  = (double*)(ws + 8388608);                      // 512 doubles
  double* cssp  = (double*)(ws + 8388608 + 4096);               // 1000 doubles
  int*    cntp  = (int*)   (ws + 8388608 + 4096 + 8000);        // 1000 ints (pad 4096)
  double* frobp = (double*)(ws + 8388608 + 4096 + 8000 + 4096); // 136 doubles

  kprep<<<512 + N_CLS, 256, 0, stream>>>(A, target, Ab, rowp, cssp, cntp);
  kgram<<<NTIL, 512, 0, stream>>>(Ab, frobp);
  kfinal<<<1, 256, 0, stream>>>(rowp, cssp, cntp, frobp, out);
}

// Round 18
// 46.994 us; speedup vs baseline: 1.3096x; 1.0483x over previous
//
#include <hip/hip_runtime.h>
#include <hip/hip_bf16.h>

// AlignmentLoss: loss = -(sum(tril(G,-1)*eq) / (sum(tril(eq,-1)) * ||tril(G,-1)||_F))
// with G = A A^T, A: 4096x1024 fp32, target: 4096 int32 (classes < 1000).
//
//   S1 = 0.5*(sum_c ||s_c||^2 - sum_i ||a_i||^2)
//   S2 = 0.5*(sum_c n_c^2 - N)
//   S3 = sum_{i>j} g_ij^2  (lower-triangle 256^2 tiles, masked Frobenius)
//   loss = -S1 / (S2 * sqrt(S3))
//
// R18 = R17 with the compile fix (no LDS pointer array -- named buffers +
// wave-uniform ternary select).  The change under test is still T4: counted
// vmcnt(8) at K-tile boundaries with depth-2 stage-ahead, vs R12's drain-0.

typedef __attribute__((ext_vector_type(8))) short short8;
typedef __attribute__((ext_vector_type(4))) float f32x4;

#define N_ROWS 4096
#define D_DIM  1024
#define N_CLS  1000
#define NTIL   136         // 16*17/2 lower-triangle 256^2 tiles
#define NKT    16          // 1024 / BK, BK = 64

__device__ __forceinline__ unsigned short f2bf(float f) {
  unsigned u = __float_as_uint(f);
  u += 0x7fffu + ((u >> 16) & 1u);   // round-to-nearest-even
  return (unsigned short)(u >> 16);
}

__device__ __forceinline__ void gload16(const short* g, const char* l) {
  __builtin_amdgcn_global_load_lds(
      (const __attribute__((address_space(1))) unsigned*)g,
      (__attribute__((address_space(3))) unsigned*)(void*)l, 16, 0, 0);
}

// ---------------------------------------------------------------------------
// kconv: A fp32 -> Ab bf16 + per-block fp64 row-norm partials.  512 x 256.
// ---------------------------------------------------------------------------
__global__ void __launch_bounds__(256) kconv(const float* __restrict__ A,
                                             short* __restrict__ Ab,
                                             double* __restrict__ rowp) {
  __shared__ double wr2[4];
  const int tid = threadIdx.x, lane = tid & 63, w = tid >> 6;
  const int row0 = blockIdx.x * 8;
  double ls = 0.0;
#pragma unroll
  for (int rr = 0; rr < 2; ++rr) {
    const int i = row0 + w * 2 + rr;
    const float4* src = (const float4*)(A + (size_t)i * D_DIM);
    short4* dst = (short4*)(Ab + (size_t)i * D_DIM);
    float s = 0.f;
#pragma unroll
    for (int c = 0; c < 4; ++c) {
      const float4 v = src[lane + c * 64];
      s += v.x * v.x + v.y * v.y + v.z * v.z + v.w * v.w;
      short4 o;
      o.x = (short)f2bf(v.x); o.y = (short)f2bf(v.y);
      o.z = (short)f2bf(v.z); o.w = (short)f2bf(v.w);
      dst[lane + c * 64] = o;
    }
#pragma unroll
    for (int off = 32; off; off >>= 1) s += __shfl_down(s, off);
    if (lane == 0) ls += (double)s;
  }
  if (lane == 0) wr2[w] = ls;
  __syncthreads();
  if (tid == 0) rowp[blockIdx.x] = wr2[0] + wr2[1] + wr2[2] + wr2[3];
}

// ---------------------------------------------------------------------------
// kmain: blocks 0..135 = 256^2 gram tile (4-phase/K-tile, counted vmcnt);
//        blocks 136..  = per-class reduction (fills the idle CUs).
// ---------------------------------------------------------------------------
__global__ void __launch_bounds__(512, 2) kmain(const float* __restrict__ A,
                                                const int* __restrict__ target,
                                                const short* __restrict__ Ab,
                                                double* __restrict__ frobp,
                                                double* __restrict__ cssp,
                                                int* __restrict__ cntp) {
  __shared__ __align__(16) char smem[131072];   // 128 KB pool
  const int tid = threadIdx.x, lane = tid & 63, w = tid >> 6;

  if (blockIdx.x < NTIL) {
    // ---------------- gram tile ----------------
    // bijective XCD swizzle: 136 = 8 * 17
    const int b = (blockIdx.x & 7) * 17 + (blockIdx.x >> 3);
    int bi = (int)((sqrtf(8.f * (float)b + 1.f) - 1.f) * 0.5f);
    while ((bi + 1) * (bi + 2) / 2 <= b) ++bi;
    while (bi * (bi + 1) / 2 > b) --bi;
    const int bj = b - bi * (bi + 1) / 2;
    const bool diag = (bi == bj);

    const short* Pa = Ab + (size_t)(bi * 256) * D_DIM;
    const short* Pb = Ab + (size_t)(bj * 256) * D_DIM;

    // LDS: per buf per matrix 32 KB = [2 ksub][256 rows][64 B]
    short* const As0 = (short*)smem;
    short* const As1 = (short*)(smem + 32768);
    short* const Bs0 = (short*)(smem + 65536);
    short* const Bs1 = (short*)(smem + 98304);

    f32x4 acc[8][4];
#pragma unroll
    for (int m = 0; m < 8; ++m)
#pragma unroll
      for (int n = 0; n < 4; ++n) acc[m][n] = (f32x4){0.f, 0.f, 0.f, 0.f};

    const int wm = w >> 2, wn = w & 3;       // wave: rows wm*128, cols wn*64
    const int row16 = lane & 15, ck = lane >> 4;

    // staging: per (matrix, half h, K-tile): 2 gload16/thread; 8/thread/tile
    const int sr = tid >> 2;                 // 0..127
    const int scS = (tid & 3) ^ ((sr >> 1) & 3);

#define STAGEU(P, BUF, h, kt)                                               \
    do {                                                                    \
      const short* _g = (P) + ((size_t)((h) * 128 + sr)) * D_DIM + (kt) * 64 + scS * 8; \
      gload16(_g,      (const char*)(BUF) + (h) * 8192 + w * 1024);         \
      gload16(_g + 32, (const char*)(BUF) + 16384 + (h) * 8192 + w * 1024); \
    } while (0)

#define STAGET(AB, BB, kt)                                                  \
    do {                                                                    \
      STAGEU(Pa, AB, 0, kt); STAGEU(Pa, AB, 1, kt);                         \
      STAGEU(Pb, BB, 0, kt); STAGEU(Pb, BB, 1, kt);                         \
    } while (0)

#define RD_A(BUF, MH)                                                       \
    _Pragma("unroll") for (int ks = 0; ks < 2; ++ks)                        \
    _Pragma("unroll") for (int m = 0; m < 4; ++m) {                         \
      const int R = wm * 128 + ((MH) * 4 + m) * 16 + row16;                 \
      a[ks][m] = *(const short8*)((const char*)(BUF) + ks * 16384 + R * 64  \
                                  + ((ck ^ ((R >> 1) & 3)) << 4));          \
    }
#define RD_B(DST, BUF, NH)                                                  \
    _Pragma("unroll") for (int ks = 0; ks < 2; ++ks)                        \
    _Pragma("unroll") for (int n = 0; n < 2; ++n) {                         \
      const int R = wn * 64 + ((NH) * 2 + n) * 16 + row16;                  \
      DST[ks][n] = *(const short8*)((const char*)(BUF) + ks * 16384 + R * 64\
                                    + ((ck ^ ((R >> 1) & 3)) << 4));        \
    }
#define PH_MFMA(MO, NO, BB)                                                 \
    __builtin_amdgcn_s_setprio(1);                                          \
    _Pragma("unroll") for (int ks = 0; ks < 2; ++ks)                        \
    _Pragma("unroll") for (int m = 0; m < 4; ++m)                           \
    _Pragma("unroll") for (int n = 0; n < 2; ++n)                           \
      acc[(MO) + m][(NO) + n] = __builtin_amdgcn_mfma_f32_16x16x32_bf16(    \
          a[ks][m], BB[ks][n], acc[(MO) + m][(NO) + n], 0, 0, 0);           \
    __builtin_amdgcn_s_setprio(0);
#define BAR __builtin_amdgcn_s_barrier()
#define SBZ __builtin_amdgcn_sched_barrier(0)

    // prologue: T0 -> buf0, drain; T1 -> buf1 stays in flight
    STAGET(As0, Bs0, 0);
    asm volatile("s_waitcnt vmcnt(0)" ::: "memory");
    SBZ;
    BAR;
    STAGET(As1, Bs1, 1);

#pragma unroll 1
    for (int t = 0; t < NKT; ++t) {
      const int c = t & 1;
      short* const As = c ? As1 : As0;     // wave-uniform select
      short* const Bs = c ? Bs1 : Bs0;
      short8 a[2][4], bq0[2][2], b1[2][2];
      // ---- ph1: q0 = rows 0-3 x cols 0-1
      RD_A(As, 0); RD_B(bq0, Bs, 0);
      BAR;
      PH_MFMA(0, 0, bq0);
      BAR;
      // ---- ph2: q1 = rows 0-3 x cols 2-3
      RD_B(b1, Bs, 1);
      BAR;
      PH_MFMA(0, 2, b1);
      BAR;
      // ---- ph3: q2 = rows 4-7 x cols 2-3  (last reads of buf c)
      RD_A(As, 1);
      BAR;
      PH_MFMA(4, 2, b1);
      BAR;                          // all reads of buf c retired
      // ---- ph4: stage T(t+2) into buf c (now free); q3 = rows 4-7 x cols 0-1
      if (t + 2 < NKT) STAGET(As, Bs, t + 2);
      PH_MFMA(4, 0, bq0);
      // ---- boundary: T(t+1) must be resident; T(t+2)'s 8 stay in flight
      if (t + 2 < NKT) {
        asm volatile("s_waitcnt vmcnt(8)" ::: "memory");
      } else if (t + 1 < NKT) {
        asm volatile("s_waitcnt vmcnt(0)" ::: "memory");
      }
      SBZ;
      BAR;
    }
#undef STAGEU
#undef STAGET
#undef RD_A
#undef RD_B
#undef PH_MFMA
#undef BAR
#undef SBZ

    // epilogue: masked Frobenius
    float fs = 0.f;
    if (!diag) {
#pragma unroll
      for (int m = 0; m < 8; ++m)
#pragma unroll
        for (int n = 0; n < 4; ++n)
#pragma unroll
          for (int q = 0; q < 4; ++q) fs += acc[m][n][q] * acc[m][n][q];
    } else {
      const int rbase = (lane >> 4) * 4, cbase = lane & 15;
#pragma unroll
      for (int m = 0; m < 8; ++m)
#pragma unroll
        for (int n = 0; n < 4; ++n)
#pragma unroll
          for (int q = 0; q < 4; ++q) {
            const int rl = wm * 128 + m * 16 + rbase + q;
            const int cl = wn * 64 + n * 16 + cbase;
            if (rl > cl) fs += acc[m][n][q] * acc[m][n][q];
          }
    }
#pragma unroll
    for (int off = 32; off; off >>= 1) fs += __shfl_down(fs, off);
    double* wredd = (double*)smem;       // LDS free after the loop
    __syncthreads();
    if (lane == 0) wredd[w] = (double)fs;
    __syncthreads();
    if (tid == 0) {
      double t = 0.0;
#pragma unroll
      for (int i = 0; i < 8; ++i) t += wredd[i];
      frobp[b] = t;
    }
  } else {
    // ---------------- per-class reduction (512 thr, 2 dims/thread) --------
    int* list = (int*)smem;                      // 16 KB
    int* lcnt = (int*)(smem + 16384);
    float* wredf = (float*)(smem + 16400);       // 8 floats
    const int c = blockIdx.x - NTIL;
    if (c >= N_CLS) return;
    if (tid == 0) *lcnt = 0;
    __syncthreads();
    for (int j = tid; j < N_ROWS; j += 512)
      if (target[j] == c) { int p = atomicAdd(lcnt, 1); list[p] = j; }
    __syncthreads();
    const int n = *lcnt;
    float2 acc = make_float2(0.f, 0.f);
    for (int m = 0; m < n; ++m) {
      const float2 v = *(const float2*)(A + (size_t)list[m] * D_DIM + tid * 2);
      acc.x += v.x; acc.y += v.y;
    }
    float s = acc.x * acc.x + acc.y * acc.y;
#pragma unroll
    for (int off = 32; off; off >>= 1) s += __shfl_down(s, off);
    if (lane == 0) wredf[w] = s;
    __syncthreads();
    if (tid == 0) {
      float t = 0.f;
#pragma unroll
      for (int i = 0; i < 8; ++i) t += wredf[i];
      cssp[c] = (double)t;
      cntp[c] = n;
    }
  }
}

// ---------------------------------------------------------------------------
// kfinal: fp64 reduce + scalar math.
// ---------------------------------------------------------------------------
__global__ void __launch_bounds__(256) kfinal(const double* __restrict__ rowp,
                                              const double* __restrict__ cssp,
                                              const int* __restrict__ cntp,
                                              const double* __restrict__ frobp,
                                              float* __restrict__ out) {
  __shared__ double red[256];
  const int tid = threadIdx.x;
  double lsum = rowp[tid] + rowp[tid + 256];
  double lcss = 0.0, lcnn = 0.0, lfr = 0.0;
  for (int c = tid; c < N_CLS; c += 256) {
    lcss += cssp[c];
    const double nc = (double)cntp[c];
    lcnn += nc * nc;
  }
  if (tid < NTIL) lfr = frobp[tid];

  double vals[4] = {lsum, lcss, lcnn, lfr};
  double res[4];
  for (int v = 0; v < 4; ++v) {
    red[tid] = vals[v];
    __syncthreads();
    for (int s = 128; s; s >>= 1) {
      if (tid < s) red[tid] += red[tid + s];
      __syncthreads();
    }
    res[v] = red[0];
    __syncthreads();
  }
  if (tid == 0) {
    const double sumr = res[0], css = res[1], cnn = res[2], frob = res[3];
    const double S1 = 0.5 * (css - sumr);
    const double S2 = 0.5 * (cnn - (double)N_ROWS);
    const double S3 = frob;
    out[0] = (float)(-(S1 / (S2 * sqrt(S3))));
  }
}

extern "C" void kernel_launch(void* const* d_in, const int* in_sizes, int n_in,
                              void* d_out, int out_size, void* d_ws, size_t ws_size,
                              hipStream_t stream) {
  const float* A = (const float*)d_in[0];
  const int* target = (const int*)d_in[1];
  float* out = (float*)d_out;

  char* ws = (char*)d_ws;
  short*  Ab    = (short*)ws;                                   // 8,388,608 B
  double* rowp  = (double*)(ws + 8388608);                      // 512 doubles
  double* cssp  = (double*)(ws + 8388608 + 4096);               // 1000 doubles
  int*    cntp  = (int*)   (ws + 8388608 + 4096 + 8000);        // 1000 ints (pad 4096)
  double* frobp = (double*)(ws + 8388608 + 4096 + 8000 + 4096); // 136 doubles

  kconv<<<512, 256, 0, stream>>>(A, Ab, rowp);
  kmain<<<NTIL + N_CLS, 512, 0, stream>>>(A, target, Ab, frobp, cssp, cntp);
  kfinal<<<1, 256, 0, stream>>>(rowp, cssp, cntp, frobp, out);
}